// Round 7
// baseline (323.707 us; speedup 1.0000x reference)
//
#include <hip/hip_runtime.h>
#include <math.h>

#define PP 4096

typedef __attribute__((ext_vector_type(8))) short short8;
typedef __attribute__((ext_vector_type(4))) short short4v;
typedef __attribute__((ext_vector_type(4))) float float4v;

__device__ __forceinline__ short f2bf(float f) {
    union { float f; unsigned u; } v; v.f = f;
    unsigned r = v.u + 0x7FFFu + ((v.u >> 16) & 1u);
    return (short)(r >> 16);
}

#if __has_builtin(__builtin_amdgcn_mfma_f32_16x16x16bf16_1k)
__device__ __forceinline__ float4v mfma16(short4v a, short4v b, float4v c) {
    return __builtin_amdgcn_mfma_f32_16x16x16bf16_1k(a, b, c, 0, 0, 0);
}
#else
__device__ __forceinline__ float4v mfma16(short4v a, short4v b, float4v c) {
    short8 a8 = {a[0], a[1], a[2], a[3], 0, 0, 0, 0};
    short8 b8 = {b[0], b[1], b[2], b[3], 0, 0, 0, 0};
    return __builtin_amdgcn_mfma_f32_16x16x32_bf16(a8, b8, c, 0, 0, 0);
}
#endif

// Grid barrier for a fully-resident grid (512 blocks x 512 thr, 2 blocks/CU).
// Release/acquire at agent scope publishes normal stores across XCD L2s.
// Bounded spin (~100x margin over worst legit wait) so a bug can't hang.
__device__ __forceinline__ void gbar(unsigned* c, unsigned nb) {
    __syncthreads();
    if (threadIdx.x == 0) {
        __threadfence();
        __hip_atomic_fetch_add(c, 1u, __ATOMIC_RELEASE, __HIP_MEMORY_SCOPE_AGENT);
        long t = 0;
        while (__hip_atomic_load(c, __ATOMIC_ACQUIRE, __HIP_MEMORY_SCOPE_AGENT) < nb
               && t < 5000000L) ++t;
        __threadfence();
    }
    __syncthreads();
}

// ---------------------------------------------------------------------------
// Mega-kernel: phase0 qkv -> phase1 attn -> phase2 gate -> phase3 mul,
// separated by grid barriers. grid = 512 blocks x 512 threads.
// LDS 36.9 KB, VGPR <= 128 => 2 blocks/CU resident (160 KB LDS, 2048 thr).
// ---------------------------------------------------------------------------
__global__ __launch_bounds__(512, 4) void mega_kernel(
    const float* __restrict__ ftr, const float* __restrict__ wq, const float* __restrict__ bq,
    const float* __restrict__ wk, const float* __restrict__ bk,
    const float* __restrict__ wv, const float* __restrict__ bv,
    const float* __restrict__ delta,
    const float* __restrict__ w_avg1, const float* __restrict__ w_avg2,
    const float* __restrict__ w_max1, const float* __restrict__ w_max2,
    short* __restrict__ q16, short* __restrict__ k16, short* __restrict__ v_a,
    float* __restrict__ psum, float* __restrict__ pmax, float* __restrict__ gate,
    unsigned* __restrict__ ctr,
    float* __restrict__ out)
{
    __shared__ float smem[9216] __attribute__((aligned(16)));

    const int tid  = threadIdx.x;
    const int b    = blockIdx.x >> 7;
    const int blk7 = blockIdx.x & 127;

    // ================= Phase 0: qkv projections (32 p per block) ==========
    {
        float* xs   = smem;            // [64][36]
        float* wvs  = smem + 2304;     // [64][68]
        float* wq_t = smem + 6656;     // [64][20]
        float* wk_t = smem + 7936;     // [64][20]
        const int p0 = blk7 << 5;

        {   // staging: 512 threads
            int idx = tid;             // xs: 512 float4s
            {
                int c = idx >> 3, j4 = (idx & 7) << 2;
                *(float4*)&xs[c * 36 + j4] =
                    *(const float4*)(ftr + ((size_t)(b * 64 + c)) * PP + p0 + j4);
            }
            #pragma unroll
            for (int r2 = 0; r2 < 2; ++r2) {   // wvs: 1024 float4s
                int i2 = tid + r2 * 512;
                int r = i2 >> 4, j4 = (i2 & 15) << 2;
                *(float4*)&wvs[r * 68 + j4] = *(const float4*)(wv + r * 64 + j4);
            }
            #pragma unroll
            for (int r2 = 0; r2 < 2; ++r2) {   // wq/wk transposed
                int i2 = tid + r2 * 512;
                int o = i2 >> 6, c2 = i2 & 63;
                wq_t[c2 * 20 + o] = wq[i2];
                wk_t[c2 * 20 + o] = wk[i2];
            }
        }
        __syncthreads();

        if (tid < 256) {
            // ---- v -> x16 A-fragment layout ----
            const int wg = tid >> 6, qd = (tid >> 4) & 3, cc = tid & 15;
            const int c = wg * 16 + cc;
            const float bvc = bv[c];
            const int col = qd * 8;
            float a[8] = {0.f,0.f,0.f,0.f,0.f,0.f,0.f,0.f};
            #pragma unroll 8
            for (int c2 = 0; c2 < 64; ++c2) {
                float w = wvs[c * 68 + c2];
                float4 xa = *(const float4*)&xs[c2 * 36 + col];
                float4 xb = *(const float4*)&xs[c2 * 36 + col + 4];
                a[0] += w * xa.x; a[1] += w * xa.y; a[2] += w * xa.z; a[3] += w * xa.w;
                a[4] += w * xb.x; a[5] += w * xb.y; a[6] += w * xb.z; a[7] += w * xb.w;
            }
            const int ptg = (p0 >> 4) + (qd >> 1);
            const int qp0 = (qd & 1) * 2;
            #pragma unroll
            for (int h = 0; h < 2; ++h) {
                short4v pv;
                #pragma unroll
                for (int j = 0; j < 4; ++j) pv[j] = f2bf(a[h * 4 + j] + bvc);
                *(short4v*)(v_a + ((((size_t)(b * 256 + ptg)) * 4 + wg) * 64 + (qp0 + h) * 16 + cc) * 4) = pv;
            }
        } else {
            // ---- q/k ----
            const int t = tid - 256;
            const int p_l = t >> 3, sel = t & 7;
            const int ch = sel & 1, half = (sel >> 1) & 1, arr = sel >> 2;
            const float* Wtr = arr ? wk_t : wq_t;
            float a[8] = {0.f,0.f,0.f,0.f,0.f,0.f,0.f,0.f};
            const int c2lo = ch * 32;
            #pragma unroll 8
            for (int c2i = 0; c2i < 32; ++c2i) {
                const int c2 = c2lo + c2i;
                float x = xs[c2 * 36 + p_l];
                float4 wA = *(const float4*)(Wtr + c2 * 20 + half * 8);
                float4 wB = *(const float4*)(Wtr + c2 * 20 + half * 8 + 4);
                a[0] += wA.x * x; a[1] += wA.y * x; a[2] += wA.z * x; a[3] += wA.w * x;
                a[4] += wB.x * x; a[5] += wB.y * x; a[6] += wB.z * x; a[7] += wB.w * x;
            }
            #pragma unroll
            for (int oo = 0; oo < 8; ++oo) a[oo] += __shfl_xor(a[oo], 1);
            if (ch == 0) {
                const float* bias = arr ? bk : bq;
                const float scl = arr ? 1.0f : 1.4426950408889634f;
                short8 pq;
                #pragma unroll
                for (int oo = 0; oo < 8; ++oo)
                    pq[oo] = f2bf((a[oo] + bias[half * 8 + oo]) * scl);
                short* dst = (arr ? k16 : q16) + (((size_t)(b * PP + p0 + p_l)) << 4) + half * 8;
                *(short8*)dst = pq;
            }
        }
    }

    gbar(ctr + 0, gridDim.x);

    // ================= Phase 1: MFMA flash attention ======================
    {
        float* Obuf = smem;            // [8][16][34]
        float* lb   = smem + 4352;     // [8][32]
        float* lfin = smem + 4608;     // [32]

        const int qblk = blk7;
        const int q0   = qblk << 5;
        const int lane = tid & 63;
        const int n    = lane & 15;
        const int quad = lane >> 4;
        const int ph   = tid >> 6;

        const float4v zf4 = {0.f, 0.f, 0.f, 0.f};

        short4v bkf[2];
        #pragma unroll
        for (int nt = 0; nt < 2; ++nt)
            bkf[nt] = *(const short4v*)(k16 + ((size_t)(b * PP + q0 + nt * 16 + n) << 4) + quad * 4);

        const short* qrow = q16 + ((size_t)(b * PP + n) << 4) + quad * 4;
        const short* vrow = v_a + (size_t)b * 262144 + lane * 4;

        float4v acc[4][2];
        #pragma unroll
        for (int mt = 0; mt < 4; ++mt)
            #pragma unroll
            for (int nt = 0; nt < 2; ++nt) acc[mt][nt] = zf4;
        float lsum[2] = {0.f, 0.f};

        const int pt0 = ph * 512;
        for (int it = 0; it < 8; ++it) {
            const int pt = pt0 + it * 64;
            const int pti = pt >> 4;

            short4v aq[4];
            #pragma unroll
            for (int f = 0; f < 4; ++f)
                aq[f] = *(const short4v*)(qrow + (size_t)(pt + f * 16) * 16);

            float4v sf_c[2], sf_n[2];
            #pragma unroll
            for (int nt = 0; nt < 2; ++nt)
                sf_c[nt] = mfma16(aq[0], bkf[nt], zf4);

            #pragma unroll
            for (int h = 0; h < 2; ++h) {
                short4v va[2][4];
                #pragma unroll
                for (int j = 0; j < 2; ++j)
                    #pragma unroll
                    for (int mt = 0; mt < 4; ++mt)
                        va[j][mt] = *(const short4v*)(vrow + (size_t)((pti + 2 * h + j) * 4 + mt) * 256);

                #pragma unroll
                for (int j = 0; j < 2; ++j) {
                    const int f = 2 * h + j;
                    if (f < 3) {
                        #pragma unroll
                        for (int nt = 0; nt < 2; ++nt)
                            sf_n[nt] = mfma16(aq[f + 1], bkf[nt], zf4);
                    }
                    short4v w[2];
                    #pragma unroll
                    for (int nt = 0; nt < 2; ++nt) {
                        float w0 = __builtin_amdgcn_exp2f(sf_c[nt][0]);
                        float w1 = __builtin_amdgcn_exp2f(sf_c[nt][1]);
                        float w2 = __builtin_amdgcn_exp2f(sf_c[nt][2]);
                        float w3 = __builtin_amdgcn_exp2f(sf_c[nt][3]);
                        lsum[nt] += (w0 + w1) + (w2 + w3);
                        union { uint2 u; short4v s; } cv;
                        cv.u.x = __builtin_amdgcn_perm(__float_as_uint(w1), __float_as_uint(w0), 0x07060302u);
                        cv.u.y = __builtin_amdgcn_perm(__float_as_uint(w3), __float_as_uint(w2), 0x07060302u);
                        w[nt] = cv.s;
                    }
                    #pragma unroll
                    for (int mt = 0; mt < 4; ++mt)
                        #pragma unroll
                        for (int nt = 0; nt < 2; ++nt)
                            acc[mt][nt] = mfma16(va[j][mt], w[nt], acc[mt][nt]);
                    #pragma unroll
                    for (int nt = 0; nt < 2; ++nt) sf_c[nt] = sf_n[nt];
                }
            }
        }

        // ---- epilogue ----
        lsum[0] += __shfl_xor(lsum[0], 16); lsum[0] += __shfl_xor(lsum[0], 32);
        lsum[1] += __shfl_xor(lsum[1], 16); lsum[1] += __shfl_xor(lsum[1], 32);
        if (quad == 0) {
            lb[ph * 32 + n]      = lsum[0];
            lb[ph * 32 + 16 + n] = lsum[1];
        }
        __syncthreads();
        if (tid < 32) {
            float s = 0.f;
            #pragma unroll
            for (int p8 = 0; p8 < 8; ++p8) s += lb[p8 * 32 + tid];
            lfin[tid] = delta[0] / s;
        }
        __syncthreads();

        const int c_l = tid >> 5;
        const int q   = tid & 31;
        #pragma unroll
        for (int mt = 0; mt < 4; ++mt) {
            #pragma unroll
            for (int nt = 0; nt < 2; ++nt)
                #pragma unroll
                for (int i = 0; i < 4; ++i)
                    Obuf[(ph * 16 + quad * 4 + i) * 34 + nt * 16 + n] = acc[mt][nt][i];
            __syncthreads();
            const int c = mt * 16 + c_l;
            float o = 0.f;
            #pragma unroll
            for (int p8 = 0; p8 < 8; ++p8) o += Obuf[(p8 * 16 + c_l) * 34 + q];
            const size_t g = ((size_t)(b * 64 + c)) * PP + q0 + q;
            o = o * lfin[q] + ftr[g];
            out[g] = o;
            float s = o, m = o;
            s += __shfl_xor(s, 1); s += __shfl_xor(s, 2);
            s += __shfl_xor(s, 4); s += __shfl_xor(s, 8); s += __shfl_xor(s, 16);
            m = fmaxf(m, __shfl_xor(m, 1)); m = fmaxf(m, __shfl_xor(m, 2));
            m = fmaxf(m, __shfl_xor(m, 4)); m = fmaxf(m, __shfl_xor(m, 8));
            m = fmaxf(m, __shfl_xor(m, 16));
            if (q == 0) {
                psum[((size_t)(b * 128) + qblk) * 64 + c] = s;
                pmax[((size_t)(b * 128) + qblk) * 64 + c] = m;
            }
            __syncthreads();
        }
    }

    gbar(ctr + 1, gridDim.x);

    // ================= Phase 2: stats reduce + SE gate (blocks 0-3) =======
    if (blockIdx.x < 4) {
        float* ss = smem;          // [4][64]
        float* sm = smem + 256;    // [4][64]
        float* fa = smem + 512;    // [64]
        float* fm = smem + 576;    // [64]
        float* ha = smem + 640;    // [16]
        float* hm = smem + 656;    // [16]
        const int bb = blockIdx.x;
        if (tid < 256) {
            const int c = tid & 63, ch = tid >> 6;
            float s = 0.f, m = -3.4e38f;
            for (int i = 0; i < 32; ++i) {
                const int qb = ch * 32 + i;
                s += psum[((size_t)(bb * 128) + qb) * 64 + c];
                m = fmaxf(m, pmax[((size_t)(bb * 128) + qb) * 64 + c]);
            }
            ss[ch * 64 + c] = s; sm[ch * 64 + c] = m;
        }
        __syncthreads();
        if (tid < 64) {
            fa[tid] = (ss[tid] + ss[64 + tid] + ss[128 + tid] + ss[192 + tid]) * (1.f / 4096.f);
            fm[tid] = fmaxf(fmaxf(sm[tid], sm[64 + tid]), fmaxf(sm[128 + tid], sm[192 + tid]));
        }
        __syncthreads();
        if (tid < 16) {
            float a = 0.f;
            for (int cc = 0; cc < 64; ++cc) a += fa[cc] * w_avg1[tid * 64 + cc];
            ha[tid] = fmaxf(a, 0.f);
        } else if (tid < 32) {
            float a = 0.f;
            for (int cc = 0; cc < 64; ++cc) a += fm[cc] * w_max1[(tid - 16) * 64 + cc];
            hm[tid - 16] = fmaxf(a, 0.f);
        }
        __syncthreads();
        if (tid < 64) {
            float a = 0.f, mm = 0.f;
            #pragma unroll
            for (int i = 0; i < 16; ++i) {
                a  += ha[i] * w_avg2[tid * 16 + i];
                mm += hm[i] * w_max2[tid * 16 + i];
            }
            gate[bb * 64 + tid] = 1.f / (1.f + expf(-(a + mm)));
        }
    }

    gbar(ctr + 2, gridDim.x);

    // ================= Phase 3: gate multiply =============================
    {
        const int idx = blockIdx.x * 512 + tid;     // 262144 float4s
        const float g = gate[idx >> 10];
        const size_t e = (size_t)idx * 4;
        float4 v = *(const float4*)(out + e);
        v.x *= g; v.y *= g; v.z *= g; v.w *= g;
        *(float4*)(out + e) = v;
    }
}

// ---------------------------------------------------------------------------
extern "C" void kernel_launch(void* const* d_in, const int* in_sizes, int n_in,
                              void* d_out, int out_size, void* d_ws, size_t ws_size,
                              hipStream_t stream)
{
    const float* ftr    = (const float*)d_in[0];
    const float* wq     = (const float*)d_in[1];
    const float* bq     = (const float*)d_in[2];
    const float* wk     = (const float*)d_in[3];
    const float* bk     = (const float*)d_in[4];
    const float* wv     = (const float*)d_in[5];
    const float* bv     = (const float*)d_in[6];
    const float* delta  = (const float*)d_in[7];
    const float* w_avg1 = (const float*)d_in[8];
    const float* w_avg2 = (const float*)d_in[9];
    const float* w_max1 = (const float*)d_in[10];
    const float* w_max2 = (const float*)d_in[11];
    float* out = (float*)d_out;

    short* wsS  = (short*)d_ws;
    short* q16  = wsS;                 // 512 KB
    short* k16  = wsS + 262144;        // 512 KB
    short* v_a  = wsS + 524288;        // 2 MB
    float* fbase = (float*)(wsS + 1572864);
    float* psum = fbase;               // 32768 floats
    float* pmax = fbase + 32768;
    float* gate = fbase + 65536;
    unsigned* ctr = (unsigned*)(fbase + 66048);

    hipMemsetAsync(ctr, 0, 128, stream);
    mega_kernel<<<512, 512, 0, stream>>>(
        ftr, wq, bq, wk, bk, wv, bv, delta, w_avg1, w_avg2, w_max1, w_max2,
        q16, k16, v_a, psum, pmax, gate, ctr, out);
}

// Round 8
// 231.272 us; speedup vs baseline: 1.3997x; 1.3997x over previous
//
#include <hip/hip_runtime.h>
#include <math.h>

#define PP 4096

typedef __attribute__((ext_vector_type(8))) short short8;
typedef __attribute__((ext_vector_type(4))) short short4v;
typedef __attribute__((ext_vector_type(4))) float float4v;

__device__ __forceinline__ short f2bf(float f) {
    union { float f; unsigned u; } v; v.f = f;
    unsigned r = v.u + 0x7FFFu + ((v.u >> 16) & 1u);
    return (short)(r >> 16);
}

#if __has_builtin(__builtin_amdgcn_mfma_f32_16x16x16bf16_1k)
__device__ __forceinline__ float4v mfma16(short4v a, short4v b, float4v c) {
    return __builtin_amdgcn_mfma_f32_16x16x16bf16_1k(a, b, c, 0, 0, 0);
}
#else
__device__ __forceinline__ float4v mfma16(short4v a, short4v b, float4v c) {
    short8 a8 = {a[0], a[1], a[2], a[3], 0, 0, 0, 0};
    short8 b8 = {b[0], b[1], b[2], b[3], 0, 0, 0, 0};
    return __builtin_amdgcn_mfma_f32_16x16x32_bf16(a8, b8, c, 0, 0, 0);
}
#endif

// Grid barrier, sense-flag style: each block's lane0 does ONE atomicAdd on the
// arrival counter; the LAST arriver alone release-stores the flag; all others
// poll the (read-only) flag with s_sleep backoff -> no RMW/read contention.
// Bounded poll count so a bug degrades to wrong-answer, never a hang.
__device__ __forceinline__ void gbar(unsigned* cnt, unsigned* flag, unsigned nb) {
    __syncthreads();
    if (threadIdx.x == 0) {
        unsigned old = __hip_atomic_fetch_add(cnt, 1u, __ATOMIC_ACQ_REL,
                                              __HIP_MEMORY_SCOPE_AGENT);
        if (old == nb - 1u) {
            __hip_atomic_store(flag, 1u, __ATOMIC_RELEASE, __HIP_MEMORY_SCOPE_AGENT);
        } else {
            int guard = 0;
            while (__hip_atomic_load(flag, __ATOMIC_ACQUIRE,
                                     __HIP_MEMORY_SCOPE_AGENT) == 0u
                   && guard < 200000) {
                __builtin_amdgcn_s_sleep(32);   // ~2048 clocks between polls
                ++guard;
            }
        }
    }
    __syncthreads();
}

// ---------------------------------------------------------------------------
// Mega-kernel: phase0 qkv -> gbar -> phase1 attn -> gbar -> phase2 gate
// (redundant per block, in LDS) + phase3 mul (fused). grid = 512 x 512.
// VGPR ~64, LDS 36.9 KB -> 2 blocks/CU resident.
// ---------------------------------------------------------------------------
__global__ __launch_bounds__(512, 4) void mega_kernel(
    const float* __restrict__ ftr, const float* __restrict__ wq, const float* __restrict__ bq,
    const float* __restrict__ wk, const float* __restrict__ bk,
    const float* __restrict__ wv, const float* __restrict__ bv,
    const float* __restrict__ delta,
    const float* __restrict__ w_avg1, const float* __restrict__ w_avg2,
    const float* __restrict__ w_max1, const float* __restrict__ w_max2,
    short* __restrict__ q16, short* __restrict__ k16, short* __restrict__ v_a,
    float* __restrict__ psum, float* __restrict__ pmax,
    unsigned* __restrict__ ctr,
    float* __restrict__ out)
{
    __shared__ float smem[9216] __attribute__((aligned(16)));

    const int tid  = threadIdx.x;
    const int b    = blockIdx.x >> 7;
    const int blk7 = blockIdx.x & 127;

    // ================= Phase 0: qkv projections (32 p per block) ==========
    {
        float* xs   = smem;            // [64][36]
        float* wvs  = smem + 2304;     // [64][68]
        float* wq_t = smem + 6656;     // [64][20]
        float* wk_t = smem + 7936;     // [64][20]
        const int p0 = blk7 << 5;

        {
            int idx = tid;
            {
                int c = idx >> 3, j4 = (idx & 7) << 2;
                *(float4*)&xs[c * 36 + j4] =
                    *(const float4*)(ftr + ((size_t)(b * 64 + c)) * PP + p0 + j4);
            }
            #pragma unroll
            for (int r2 = 0; r2 < 2; ++r2) {
                int i2 = tid + r2 * 512;
                int r = i2 >> 4, j4 = (i2 & 15) << 2;
                *(float4*)&wvs[r * 68 + j4] = *(const float4*)(wv + r * 64 + j4);
            }
            #pragma unroll
            for (int r2 = 0; r2 < 2; ++r2) {
                int i2 = tid + r2 * 512;
                int o = i2 >> 6, c2 = i2 & 63;
                wq_t[c2 * 20 + o] = wq[i2];
                wk_t[c2 * 20 + o] = wk[i2];
            }
        }
        __syncthreads();

        if (tid < 256) {
            // ---- v -> x16 A-fragment layout ----
            const int wg = tid >> 6, qd = (tid >> 4) & 3, cc = tid & 15;
            const int c = wg * 16 + cc;
            const float bvc = bv[c];
            const int col = qd * 8;
            float a[8] = {0.f,0.f,0.f,0.f,0.f,0.f,0.f,0.f};
            #pragma unroll 8
            for (int c2 = 0; c2 < 64; ++c2) {
                float w = wvs[c * 68 + c2];
                float4 xa = *(const float4*)&xs[c2 * 36 + col];
                float4 xb = *(const float4*)&xs[c2 * 36 + col + 4];
                a[0] += w * xa.x; a[1] += w * xa.y; a[2] += w * xa.z; a[3] += w * xa.w;
                a[4] += w * xb.x; a[5] += w * xb.y; a[6] += w * xb.z; a[7] += w * xb.w;
            }
            const int ptg = (p0 >> 4) + (qd >> 1);
            const int qp0 = (qd & 1) * 2;
            #pragma unroll
            for (int h = 0; h < 2; ++h) {
                short4v pv;
                #pragma unroll
                for (int j = 0; j < 4; ++j) pv[j] = f2bf(a[h * 4 + j] + bvc);
                *(short4v*)(v_a + ((((size_t)(b * 256 + ptg)) * 4 + wg) * 64 + (qp0 + h) * 16 + cc) * 4) = pv;
            }
        } else {
            // ---- q/k ----
            const int t = tid - 256;
            const int p_l = t >> 3, sel = t & 7;
            const int ch = sel & 1, half = (sel >> 1) & 1, arr = sel >> 2;
            const float* Wtr = arr ? wk_t : wq_t;
            float a[8] = {0.f,0.f,0.f,0.f,0.f,0.f,0.f,0.f};
            const int c2lo = ch * 32;
            #pragma unroll 8
            for (int c2i = 0; c2i < 32; ++c2i) {
                const int c2 = c2lo + c2i;
                float x = xs[c2 * 36 + p_l];
                float4 wA = *(const float4*)(Wtr + c2 * 20 + half * 8);
                float4 wB = *(const float4*)(Wtr + c2 * 20 + half * 8 + 4);
                a[0] += wA.x * x; a[1] += wA.y * x; a[2] += wA.z * x; a[3] += wA.w * x;
                a[4] += wB.x * x; a[5] += wB.y * x; a[6] += wB.z * x; a[7] += wB.w * x;
            }
            #pragma unroll
            for (int oo = 0; oo < 8; ++oo) a[oo] += __shfl_xor(a[oo], 1);
            if (ch == 0) {
                const float* bias = arr ? bk : bq;
                const float scl = arr ? 1.0f : 1.4426950408889634f;
                short8 pq;
                #pragma unroll
                for (int oo = 0; oo < 8; ++oo)
                    pq[oo] = f2bf((a[oo] + bias[half * 8 + oo]) * scl);
                short* dst = (arr ? k16 : q16) + (((size_t)(b * PP + p0 + p_l)) << 4) + half * 8;
                *(short8*)dst = pq;
            }
        }
    }

    gbar(ctr + 0, ctr + 16, gridDim.x);

    // ================= Phase 1: MFMA flash attention ======================
    {
        float* Obuf = smem;            // [8][16][34]
        float* lb   = smem + 4352;     // [8][32]
        float* lfin = smem + 4608;     // [32]

        const int qblk = blk7;
        const int q0   = qblk << 5;
        const int lane = tid & 63;
        const int n    = lane & 15;
        const int quad = lane >> 4;
        const int ph   = tid >> 6;

        const float4v zf4 = {0.f, 0.f, 0.f, 0.f};

        short4v bkf[2];
        #pragma unroll
        for (int nt = 0; nt < 2; ++nt)
            bkf[nt] = *(const short4v*)(k16 + ((size_t)(b * PP + q0 + nt * 16 + n) << 4) + quad * 4);

        const short* qrow = q16 + ((size_t)(b * PP + n) << 4) + quad * 4;
        const short* vrow = v_a + (size_t)b * 262144 + lane * 4;

        float4v acc[4][2];
        #pragma unroll
        for (int mt = 0; mt < 4; ++mt)
            #pragma unroll
            for (int nt = 0; nt < 2; ++nt) acc[mt][nt] = zf4;
        float lsum[2] = {0.f, 0.f};

        const int pt0 = ph * 512;
        for (int it = 0; it < 8; ++it) {
            const int pt = pt0 + it * 64;
            const int pti = pt >> 4;

            short4v aq[4];
            #pragma unroll
            for (int f = 0; f < 4; ++f)
                aq[f] = *(const short4v*)(qrow + (size_t)(pt + f * 16) * 16);

            float4v sf_c[2], sf_n[2];
            #pragma unroll
            for (int nt = 0; nt < 2; ++nt)
                sf_c[nt] = mfma16(aq[0], bkf[nt], zf4);

            #pragma unroll
            for (int h = 0; h < 2; ++h) {
                short4v va[2][4];
                #pragma unroll
                for (int j = 0; j < 2; ++j)
                    #pragma unroll
                    for (int mt = 0; mt < 4; ++mt)
                        va[j][mt] = *(const short4v*)(vrow + (size_t)((pti + 2 * h + j) * 4 + mt) * 256);

                #pragma unroll
                for (int j = 0; j < 2; ++j) {
                    const int f = 2 * h + j;
                    if (f < 3) {
                        #pragma unroll
                        for (int nt = 0; nt < 2; ++nt)
                            sf_n[nt] = mfma16(aq[f + 1], bkf[nt], zf4);
                    }
                    short4v w[2];
                    #pragma unroll
                    for (int nt = 0; nt < 2; ++nt) {
                        float w0 = __builtin_amdgcn_exp2f(sf_c[nt][0]);
                        float w1 = __builtin_amdgcn_exp2f(sf_c[nt][1]);
                        float w2 = __builtin_amdgcn_exp2f(sf_c[nt][2]);
                        float w3 = __builtin_amdgcn_exp2f(sf_c[nt][3]);
                        lsum[nt] += (w0 + w1) + (w2 + w3);
                        union { uint2 u; short4v s; } cv;
                        cv.u.x = __builtin_amdgcn_perm(__float_as_uint(w1), __float_as_uint(w0), 0x07060302u);
                        cv.u.y = __builtin_amdgcn_perm(__float_as_uint(w3), __float_as_uint(w2), 0x07060302u);
                        w[nt] = cv.s;
                    }
                    #pragma unroll
                    for (int mt = 0; mt < 4; ++mt)
                        #pragma unroll
                        for (int nt = 0; nt < 2; ++nt)
                            acc[mt][nt] = mfma16(va[j][mt], w[nt], acc[mt][nt]);
                    #pragma unroll
                    for (int nt = 0; nt < 2; ++nt) sf_c[nt] = sf_n[nt];
                }
            }
        }

        // ---- epilogue ----
        lsum[0] += __shfl_xor(lsum[0], 16); lsum[0] += __shfl_xor(lsum[0], 32);
        lsum[1] += __shfl_xor(lsum[1], 16); lsum[1] += __shfl_xor(lsum[1], 32);
        if (quad == 0) {
            lb[ph * 32 + n]      = lsum[0];
            lb[ph * 32 + 16 + n] = lsum[1];
        }
        __syncthreads();
        if (tid < 32) {
            float s = 0.f;
            #pragma unroll
            for (int p8 = 0; p8 < 8; ++p8) s += lb[p8 * 32 + tid];
            lfin[tid] = delta[0] / s;
        }
        __syncthreads();

        const int c_l = tid >> 5;
        const int q   = tid & 31;
        #pragma unroll
        for (int mt = 0; mt < 4; ++mt) {
            #pragma unroll
            for (int nt = 0; nt < 2; ++nt)
                #pragma unroll
                for (int i = 0; i < 4; ++i)
                    Obuf[(ph * 16 + quad * 4 + i) * 34 + nt * 16 + n] = acc[mt][nt][i];
            __syncthreads();
            const int c = mt * 16 + c_l;
            float o = 0.f;
            #pragma unroll
            for (int p8 = 0; p8 < 8; ++p8) o += Obuf[(p8 * 16 + c_l) * 34 + q];
            const size_t g = ((size_t)(b * 64 + c)) * PP + q0 + q;
            o = o * lfin[q] + ftr[g];
            out[g] = o;
            float s = o, m = o;
            s += __shfl_xor(s, 1); s += __shfl_xor(s, 2);
            s += __shfl_xor(s, 4); s += __shfl_xor(s, 8); s += __shfl_xor(s, 16);
            m = fmaxf(m, __shfl_xor(m, 1)); m = fmaxf(m, __shfl_xor(m, 2));
            m = fmaxf(m, __shfl_xor(m, 4)); m = fmaxf(m, __shfl_xor(m, 8));
            m = fmaxf(m, __shfl_xor(m, 16));
            if (q == 0) {
                psum[((size_t)(b * 128) + qblk) * 64 + c] = s;
                pmax[((size_t)(b * 128) + qblk) * 64 + c] = m;
            }
            __syncthreads();
        }
    }

    gbar(ctr + 1, ctr + 17, gridDim.x);

    // ====== Phase 2: stats reduce + SE gate (redundant per block, in LDS) =
    {
        float* ss = smem;          // [8][64]
        float* sm = smem + 512;    // [8][64]
        float* fa = smem + 1024;   // [64]
        float* fm = smem + 1088;   // [64]
        float* ha = smem + 1152;   // [16]
        float* hm = smem + 1168;   // [16]
        float* gs = smem + 1184;   // [64] gate for this block's b

        const int c = tid & 63, ch = tid >> 6;   // ch 0..7
        float s = 0.f, m = -3.4e38f;
        #pragma unroll
        for (int i = 0; i < 16; ++i) {
            const int qb = ch * 16 + i;
            s += psum[((size_t)(b * 128) + qb) * 64 + c];
            m = fmaxf(m, pmax[((size_t)(b * 128) + qb) * 64 + c]);
        }
        ss[ch * 64 + c] = s; sm[ch * 64 + c] = m;
        __syncthreads();
        if (tid < 64) {
            float sa = 0.f, ma = -3.4e38f;
            #pragma unroll
            for (int j = 0; j < 8; ++j) {
                sa += ss[j * 64 + tid];
                ma = fmaxf(ma, sm[j * 64 + tid]);
            }
            fa[tid] = sa * (1.f / 4096.f);
            fm[tid] = ma;
        }
        __syncthreads();
        if (tid < 16) {
            float a = 0.f;
            for (int cc = 0; cc < 64; ++cc) a += fa[cc] * w_avg1[tid * 64 + cc];
            ha[tid] = fmaxf(a, 0.f);
        } else if (tid < 32) {
            float a = 0.f;
            for (int cc = 0; cc < 64; ++cc) a += fm[cc] * w_max1[(tid - 16) * 64 + cc];
            hm[tid - 16] = fmaxf(a, 0.f);
        }
        __syncthreads();
        if (tid < 64) {
            float a = 0.f, mm = 0.f;
            #pragma unroll
            for (int i = 0; i < 16; ++i) {
                a  += ha[i] * w_avg2[tid * 16 + i];
                mm += hm[i] * w_max2[tid * 16 + i];
            }
            gs[tid] = 1.f / (1.f + expf(-(a + mm)));
        }
        __syncthreads();

        // ====== Phase 3: gate multiply of this block's own slice ==========
        // Block owns 2048 floats = half of one (b, c=blk7>>1) row.
        const float g = gs[blk7 >> 1];
        const size_t e = (size_t)blockIdx.x * 2048 + tid * 4;
        float4 v = *(const float4*)(out + e);
        v.x *= g; v.y *= g; v.z *= g; v.w *= g;
        *(float4*)(out + e) = v;
    }
}

// ---------------------------------------------------------------------------
extern "C" void kernel_launch(void* const* d_in, const int* in_sizes, int n_in,
                              void* d_out, int out_size, void* d_ws, size_t ws_size,
                              hipStream_t stream)
{
    const float* ftr    = (const float*)d_in[0];
    const float* wq     = (const float*)d_in[1];
    const float* bq     = (const float*)d_in[2];
    const float* wk     = (const float*)d_in[3];
    const float* bk     = (const float*)d_in[4];
    const float* wv     = (const float*)d_in[5];
    const float* bv     = (const float*)d_in[6];
    const float* delta  = (const float*)d_in[7];
    const float* w_avg1 = (const float*)d_in[8];
    const float* w_avg2 = (const float*)d_in[9];
    const float* w_max1 = (const float*)d_in[10];
    const float* w_max2 = (const float*)d_in[11];
    float* out = (float*)d_out;

    short* wsS  = (short*)d_ws;
    short* q16  = wsS;                 // 512 KB
    short* k16  = wsS + 262144;        // 512 KB
    short* v_a  = wsS + 524288;        // 2 MB
    float* fbase = (float*)(wsS + 1572864);
    float* psum = fbase;               // 32768 floats
    float* pmax = fbase + 32768;
    unsigned* ctr = (unsigned*)(fbase + 65536);   // [0,1]=arrive, [16,17]=flag

    hipMemsetAsync(ctr, 0, 128, stream);
    mega_kernel<<<512, 512, 0, stream>>>(
        ftr, wq, bq, wk, bk, wv, bv, delta, w_avg1, w_avg2, w_max1, w_max2,
        q16, k16, v_a, psum, pmax, ctr, out);
}